// Round 3
// baseline (620.609 us; speedup 1.0000x reference)
//
#include <hip/hip_runtime.h>
#include <math.h>

#define NEGV -10000000.0f

constexpr int B_ = 8, T_ = 16;
constexpr int QALL = 256, QRES = 128, QARG = 192;
constexpr int STATE = 256, VOCAB = 10000;
constexpr int WT = 128;
constexpr int NWT = (VOCAB + WT - 1) / WT;   // 79

// ---- workspace layout (units of 4 bytes) ----
constexpr size_t OFF_CHART = 0;                                    // chart[lev][s][b][a]
constexpr size_t CHART_SZ  = (size_t)T_ * T_ * B_ * QALL;          // 524288
constexpr size_t OFF_EGR   = OFF_CHART + CHART_SZ;                 // exp(G_rarg) [j][r]
constexpr size_t OFF_EGL   = OFF_EGR + (size_t)QARG * QRES;        // exp(G_larg) [j][r]
constexpr size_t OFF_LF    = OFF_EGL + (size_t)QARG * QRES;        // lfunc transposed [j][r] (int)
constexpr size_t OFF_RF    = OFF_LF + (size_t)QARG * QRES;         // rfunc transposed [j][r] (int)
constexpr size_t OFF_S0    = OFF_RF + (size_t)QARG * QRES;         // split_scores[:,0] (256)
constexpr size_t OFF_S1    = OFF_S0 + QALL;                        // split_scores[:,1] (256)
constexpr size_t OFF_PM    = OFF_S1 + QALL;                        // emit partial max [wt][a]
constexpr size_t OFF_PS    = OFF_PM + (size_t)NWT * QALL;          // emit partial sum [wt][a]
constexpr size_t OFF_LSE   = OFF_PS + (size_t)NWT * QALL;          // emit row lse (256)
constexpr size_t OFF_RMAX  = OFF_LSE + QALL;                       // rowmax[lev][s][b] (16*16*8)
constexpr size_t OFF_ACC   = OFF_RMAX + (size_t)T_ * T_ * B_;      // exp-sum acc [slot][r] (960*128)
constexpr size_t ACC_SZ    = 960 * 128;
constexpr size_t OFF_CNT   = OFF_ACC + ACC_SZ;                     // arrival counters (960 ints)
// total ~790k floats ~ 3.2 MB

__device__ __forceinline__ size_t chIdx(int lev, int s, int b) {
    return OFF_CHART + ((size_t)((lev * 16 + s) * 8 + b)) * 256;
}

__device__ __forceinline__ float waveMax(float v) {
    #pragma unroll
    for (int m = 32; m >= 1; m >>= 1) v = fmaxf(v, __shfl_xor(v, m, 64));
    return v;
}
__device__ __forceinline__ float waveSum(float v) {
    #pragma unroll
    for (int m = 32; m >= 1; m >>= 1) v += __shfl_xor(v, m, 64);
    return v;
}
__device__ __forceinline__ float blockMax(float v, float* scr, int nw) {
    int lane = threadIdx.x & 63, w = threadIdx.x >> 6;
    v = waveMax(v);
    if (lane == 0) scr[w] = v;
    __syncthreads();
    float r = scr[0];
    for (int i = 1; i < nw; i++) r = fmaxf(r, scr[i]);
    __syncthreads();
    return r;
}
__device__ __forceinline__ float blockSum(float v, float* scr, int nw) {
    int lane = threadIdx.x & 63, w = threadIdx.x >> 6;
    v = waveSum(v);
    if (lane == 0) scr[w] = v;
    __syncthreads();
    float r = 0.f;
    for (int i = 0; i < nw; i++) r += scr[i];
    __syncthreads();
    return r;
}

// ---------------- G tables: log_softmax(rule_W+rule_b) + assoc, exp'd + transposed ----------------
__global__ __launch_bounds__(192) void prep_g_kernel(
        const float* __restrict__ rule_W, const float* __restrict__ rule_b,
        const float* __restrict__ assoc,
        const float* __restrict__ larg_mask, const float* __restrict__ rarg_mask,
        const int* __restrict__ lfunc, const int* __restrict__ rfunc,
        float* __restrict__ ws) {
    __shared__ float scr[4];
    int r = blockIdx.x;      // 0..127
    int j = threadIdx.x;     // 0..191
    float v0 = rule_W[r * 2 * QARG + j] + rule_b[j];
    float v1 = rule_W[r * 2 * QARG + QARG + j] + rule_b[QARG + j];
    float m = blockMax(fmaxf(v0, v1), scr, 3);
    float s = blockSum(expf(v0 - m) + expf(v1 - m), scr, 3);
    float l = m + logf(s);
    float av = assoc[r * QARG + j];
    float gl = v0 - l + av + larg_mask[r * QARG + j];
    float gr = v1 - l + av + rarg_mask[r * QARG + j];
    ws[OFF_EGL + (size_t)j * QRES + r] = expf(gl);
    ws[OFF_EGR + (size_t)j * QRES + r] = expf(gr);
    ((int*)ws)[OFF_LF + (size_t)j * QRES + r] = lfunc[r * QARG + j];
    ((int*)ws)[OFF_RF + (size_t)j * QRES + r] = rfunc[r * QARG + j];
}

// ---------------- split-score MLP: 4 rows per block, 64 blocks ----------------
__device__ __forceinline__ void mm4(const float IN[4][STATE],
                                    const float* __restrict__ W, const float* __restrict__ bias,
                                    int t, float o[4]) {
    float a0 = bias[t], a1 = a0, a2 = a0, a3 = a0;
    #pragma unroll 4
    for (int s = 0; s < STATE; s += 4) {
        float4 x0 = *(const float4*)&IN[0][s];
        float4 x1 = *(const float4*)&IN[1][s];
        float4 x2 = *(const float4*)&IN[2][s];
        float4 x3 = *(const float4*)&IN[3][s];
        float w0 = W[(s + 0) * STATE + t];
        float w1 = W[(s + 1) * STATE + t];
        float w2 = W[(s + 2) * STATE + t];
        float w3 = W[(s + 3) * STATE + t];
        a0 += x0.x * w0 + x0.y * w1 + x0.z * w2 + x0.w * w3;
        a1 += x1.x * w0 + x1.y * w1 + x1.z * w2 + x1.w * w3;
        a2 += x2.x * w0 + x2.y * w1 + x2.z * w2 + x2.w * w3;
        a3 += x3.x * w0 + x3.y * w1 + x3.z * w2 + x3.w * w3;
    }
    o[0] = a0; o[1] = a1; o[2] = a2; o[3] = a3;
}

__global__ __launch_bounds__(256) void mlp_kernel(
        const float* __restrict__ nt_emb,
        const float* __restrict__ sw1, const float* __restrict__ sb1,
        const float* __restrict__ r1w1, const float* __restrict__ r1b1,
        const float* __restrict__ r1w2, const float* __restrict__ r1b2,
        const float* __restrict__ r2w1, const float* __restrict__ r2b1,
        const float* __restrict__ r2w2, const float* __restrict__ r2b2,
        const float* __restrict__ sw2, const float* __restrict__ sb2,
        float* __restrict__ ws) {
    __shared__ __align__(16) float H[4][STATE], Tb[4][STATE];
    __shared__ float scr[4];
    int a0 = blockIdx.x * 4;
    int t = threadIdx.x;
    float o[4];
    #pragma unroll
    for (int rr = 0; rr < 4; rr++) Tb[rr][t] = nt_emb[(a0 + rr) * STATE + t];
    __syncthreads();
    mm4(Tb, sw1, sb1, t, o);
    __syncthreads();
    #pragma unroll
    for (int rr = 0; rr < 4; rr++) H[rr][t] = o[rr];
    __syncthreads();
    mm4(H, r1w1, r1b1, t, o);
    __syncthreads();
    #pragma unroll
    for (int rr = 0; rr < 4; rr++) Tb[rr][t] = fmaxf(o[rr], 0.f);
    __syncthreads();
    mm4(Tb, r1w2, r1b2, t, o);
    __syncthreads();
    #pragma unroll
    for (int rr = 0; rr < 4; rr++) H[rr][t] += fmaxf(o[rr], 0.f);
    __syncthreads();
    mm4(H, r2w1, r2b1, t, o);
    __syncthreads();
    #pragma unroll
    for (int rr = 0; rr < 4; rr++) Tb[rr][t] = fmaxf(o[rr], 0.f);
    __syncthreads();
    mm4(Tb, r2w2, r2b2, t, o);
    __syncthreads();
    float h[4];
    #pragma unroll
    for (int rr = 0; rr < 4; rr++) h[rr] = H[rr][t] + fmaxf(o[rr], 0.f);
    float w20 = sw2[t * 2 + 0], w21 = sw2[t * 2 + 1];
    #pragma unroll
    for (int rr = 0; rr < 4; rr++) {
        float u0 = blockSum(h[rr] * w20, scr, 4) + sb2[0];
        float u1 = blockSum(h[rr] * w21, scr, 4) + sb2[1];
        if (t == 0) {
            float mm = fmaxf(u0, u1);
            float l = mm + logf(expf(u0 - mm) + expf(u1 - mm));
            ws[OFF_S0 + a0 + rr] = u0 - l;
            ws[OFF_S1 + a0 + rr] = u1 - l;
        }
    }
}

// ---------------- emit GEMM (per-tile) with fused partial row-logsumexp ----------------
__global__ __launch_bounds__(256) void emit_kernel(
        const float* __restrict__ nt_emb, const float* __restrict__ W_emit,
        const float* __restrict__ b_emit, float* __restrict__ ws) {
    __shared__ float As[16][64];
    __shared__ float Bs[16][128];
    __shared__ float redM[64][16], redS[64][16];
    int wt = blockIdx.x, at = blockIdx.y;
    int t = threadIdx.x;
    int tx = t & 15, ty = t >> 4;
    float acc[4][8];
    #pragma unroll
    for (int i = 0; i < 4; i++)
        #pragma unroll
        for (int j = 0; j < 8; j++) acc[i][j] = 0.f;
    int wbase = wt * WT, abase = at * 64;
    for (int k0 = 0; k0 < STATE; k0 += 16) {
        {
            int idx = t * 4;
            int kk = idx & 15, aa = idx >> 4;
            float4 v = *(const float4*)&nt_emb[(abase + aa) * STATE + k0 + kk];
            As[kk + 0][aa] = v.x; As[kk + 1][aa] = v.y; As[kk + 2][aa] = v.z; As[kk + 3][aa] = v.w;
        }
        {
            int idx = t * 8;
            int kk = idx >> 7, ww = idx & 127;
            int w = wbase + ww;
            const float* src = &W_emit[(k0 + kk) * VOCAB + w];
            float4 v0, v1;
            if (w + 7 < VOCAB) {
                v0 = *(const float4*)src;
                v1 = *(const float4*)(src + 4);
            } else {
                float tv[8];
                #pragma unroll
                for (int q = 0; q < 8; q++) tv[q] = (w + q < VOCAB) ? src[q] : 0.f;
                v0 = make_float4(tv[0], tv[1], tv[2], tv[3]);
                v1 = make_float4(tv[4], tv[5], tv[6], tv[7]);
            }
            float* dst = &Bs[kk][ww];
            ((float4*)dst)[0] = v0;
            ((float4*)dst)[1] = v1;
        }
        __syncthreads();
        #pragma unroll
        for (int kk = 0; kk < 16; kk++) {
            float a4[4], b8[8];
            #pragma unroll
            for (int i = 0; i < 4; i++) a4[i] = As[kk][ty * 4 + i];
            #pragma unroll
            for (int j = 0; j < 8; j++) b8[j] = Bs[kk][tx * 8 + j];
            #pragma unroll
            for (int i = 0; i < 4; i++)
                #pragma unroll
                for (int j = 0; j < 8; j++) acc[i][j] += a4[i] * b8[j];
        }
        __syncthreads();
    }
    float be[8];
    #pragma unroll
    for (int j = 0; j < 8; j++) {
        int w = wbase + tx * 8 + j;
        be[j] = (w < VOCAB) ? b_emit[w] : 0.f;
    }
    #pragma unroll
    for (int i = 0; i < 4; i++) {
        float mloc = -3.0e38f;
        #pragma unroll
        for (int j = 0; j < 8; j++) {
            int w = wbase + tx * 8 + j;
            if (w < VOCAB) {
                float v = acc[i][j] + be[j];
                acc[i][j] = v;
                mloc = fmaxf(mloc, v);
            }
        }
        float sloc = 0.f;
        #pragma unroll
        for (int j = 0; j < 8; j++) {
            int w = wbase + tx * 8 + j;
            if (w < VOCAB) sloc += expf(acc[i][j] - mloc);
        }
        redM[ty * 4 + i][tx] = mloc;
        redS[ty * 4 + i][tx] = sloc;
    }
    __syncthreads();
    if (t < 64) {
        float M = -3.0e38f;
        #pragma unroll
        for (int i = 0; i < 16; i++) M = fmaxf(M, redM[t][i]);
        float S = 0.f;
        #pragma unroll
        for (int i = 0; i < 16; i++) S += redS[t][i] * expf(redM[t][i] - M);
        ws[OFF_PM + (size_t)wt * QALL + abase + t] = M;
        ws[OFF_PS + (size_t)wt * QALL + abase + t] = S;
    }
}

// ---------------- combine emit partials -> lse per row ----------------
__global__ __launch_bounds__(256) void lse_kernel(float* __restrict__ ws) {
    int a = threadIdx.x;
    float M = -3.0e38f;
    for (int wt = 0; wt < NWT; wt++) M = fmaxf(M, ws[OFF_PM + (size_t)wt * QALL + a]);
    float S = 0.f;
    for (int wt = 0; wt < NWT; wt++)
        S += ws[OFF_PS + (size_t)wt * QALL + a] * expf(ws[OFF_PM + (size_t)wt * QALL + a] - M);
    ws[OFF_LSE + a] = M + logf(S);
}

// ---------------- chart level 0: LDS-staged W_emit column + RMAX write ----------------
__global__ __launch_bounds__(256) void chart0_kernel(
        const int* __restrict__ words, const float* __restrict__ nt_emb,
        const float* __restrict__ W_emit, const float* __restrict__ b_emit,
        float* __restrict__ ws) {
    __shared__ float wcol[STATE];
    __shared__ float scr[4];
    int blk = blockIdx.x;            // b*16 + tp
    int b = blk >> 4, tp = blk & 15;
    int t = threadIdx.x;
    int w = words[b * T_ + tp];
    wcol[t] = W_emit[(size_t)t * VOCAB + w];
    __syncthreads();
    const float* arow = &nt_emb[t * STATE];
    float acc = 0.f;
    #pragma unroll 4
    for (int s = 0; s < STATE; s += 4) {
        float4 x = *(const float4*)&arow[s];
        acc += x.x * wcol[s] + x.y * wcol[s + 1] + x.z * wcol[s + 2] + x.w * wcol[s + 3];
    }
    float val = acc + b_emit[w] - ws[OFF_LSE + t] + ws[OFF_S1 + t];
    ws[chIdx(0, tp, b) + t] = val;
    float M = blockMax(val, scr, 4);
    if (t == 0) ws[OFF_RMAX + (size_t)(0 * 16 + tp) * 8 + b] = M;
}

// ---------------- per-level kernel: W-form GEMM + single gather, last-block finalize --------
// grid = (n*8, 12); blockIdx.y = which*6 + jt. 512 threads.
__global__ __launch_bounds__(512) void level_kernel(float* __restrict__ ws,
                                                    const int* __restrict__ argpc,
                                                    const int* __restrict__ res2all,
                                                    int ell, int lvbase) {
    __shared__ __align__(16) float eAf[15 * 256];   // exp(A - smA[k]), full rows
    __shared__ __align__(16) float eBb[15 * 32];    // exp(B[argpc[j]] - (m - smA[k])), j-tile
    __shared__ __align__(16) float Wt[32 * 256];    // W[jj][a] = sum_k eAf[k][a]*eBb[k][jj]
    __shared__ float smA[15], smB[15];
    __shared__ float Sred[512];
    __shared__ float outrow[256];
    __shared__ float scrm[8];
    __shared__ int flag;

    int sb = blockIdx.x;
    int s = sb >> 3, b = sb & 7;
    int wj = blockIdx.y;
    int which = wj / 6, jt = wj % 6;
    int jbase = jt * 32;
    int t = threadIdx.x;
    int K = ell - 1;
    int slot = (lvbase + s) * 8 + b;

    // precomputed row maxes
    if (t < K) {
        int kp = t;
        float mL = ws[OFF_RMAX + (size_t)(kp * 16 + s) * 8 + b];
        float mR = ws[OFF_RMAX + (size_t)((ell - kp - 2) * 16 + (s + kp + 1)) * 8 + b];
        smA[kp] = which ? mR : mL;
        smB[kp] = which ? mL : mR;
    }
    __syncthreads();
    float m = -3.0e38f;
    for (int kp = 0; kp < K; kp++) m = fmaxf(m, smA[kp] + smB[kp]);

    // load + exponentiate A-side full rows
    for (int i = t; i < K * 256; i += 512) {
        int kp = i >> 8, a = i & 255;
        size_t rowA = which ? chIdx(ell - kp - 2, s + kp + 1, b) : chIdx(kp, s, b);
        eAf[i] = expf(ws[rowA + a] - smA[kp]);
    }
    // load + exponentiate B-side gathered at argpc (this j-tile only)
    for (int i = t; i < K * 32; i += 512) {
        int kp = i >> 5, jj = i & 31;
        int ap = argpc[jbase + jj];
        size_t rowB = which ? chIdx(kp, s, b) : chIdx(ell - kp - 2, s + kp + 1, b);
        eBb[i] = expf(ws[rowB + ap] - (m - smA[kp]));
    }
    __syncthreads();

    // GEMM: W[jj][a] = sum_k eAf[k][a] * eBb[k][jj]; thread = (ag 4a, jg 4j)
    {
        int ag = t & 63, jg = t >> 6;
        int a0 = ag * 4, j0 = jg * 4;
        float acc[4][4];
        #pragma unroll
        for (int x = 0; x < 4; x++)
            #pragma unroll
            for (int y = 0; y < 4; y++) acc[x][y] = 0.f;
        for (int kp = 0; kp < K; kp++) {
            float4 av = *(const float4*)&eAf[kp * 256 + a0];
            float4 bv = *(const float4*)&eBb[kp * 32 + j0];
            acc[0][0] += bv.x * av.x; acc[0][1] += bv.x * av.y; acc[0][2] += bv.x * av.z; acc[0][3] += bv.x * av.w;
            acc[1][0] += bv.y * av.x; acc[1][1] += bv.y * av.y; acc[1][2] += bv.y * av.z; acc[1][3] += bv.y * av.w;
            acc[2][0] += bv.z * av.x; acc[2][1] += bv.z * av.y; acc[2][2] += bv.z * av.z; acc[2][3] += bv.z * av.w;
            acc[3][0] += bv.w * av.x; acc[3][1] += bv.w * av.y; acc[3][2] += bv.w * av.z; acc[3][3] += bv.w * av.w;
        }
        #pragma unroll
        for (int x = 0; x < 4; x++)
            *(float4*)&Wt[(size_t)(j0 + x) * 256 + a0] =
                make_float4(acc[x][0], acc[x][1], acc[x][2], acc[x][3]);
    }
    __syncthreads();

    // gather: sum_j eG[j][r] * Wt[jj][idx[j][r]]
    {
        int r = t & 127, jq = t >> 7;   // 4 groups × 8 j
        const float* eG  = ws + (which ? OFF_EGL : OFF_EGR);
        const int* idxT  = ((const int*)ws) + (which ? OFF_RF : OFF_LF);
        float sum = 0.f;
        #pragma unroll
        for (int i = 0; i < 8; i++) {
            int jj = jq * 8 + i;
            int j = jbase + jj;
            float gv = eG[(size_t)j * QRES + r];
            int idx = idxT[(size_t)j * QRES + r];
            sum += gv * Wt[(size_t)jj * 256 + idx];
        }
        Sred[t] = sum;
    }
    __syncthreads();
    if (t < 128) {
        float S = Sred[t] + Sred[t + 128] + Sred[t + 256] + Sred[t + 384];
        atomicAdd(&ws[OFF_ACC + (size_t)slot * 128 + t], S);
    }
    __syncthreads();
    if (t == 0) {
        __threadfence();
        int old = atomicAdd(&((int*)ws)[OFF_CNT + slot], 1);
        flag = (old == 11);
    }
    __syncthreads();
    if (!flag) return;
    __threadfence();

    // last block for this (s,b): finalize
    if (t < 256) outrow[t] = NEGV;
    __syncthreads();
    float pm = NEGV;
    if (t < 128) {
        float S = __hip_atomic_load(&ws[OFF_ACC + (size_t)slot * 128 + t],
                                    __ATOMIC_RELAXED, __HIP_MEMORY_SCOPE_AGENT);
        float parent = logf(S) + m + ws[OFF_S0 + res2all[t]];
        outrow[res2all[t]] = parent;
        pm = parent;
    }
    float wm = waveMax(pm);
    if ((t & 63) == 0) scrm[t >> 6] = wm;
    __syncthreads();
    if (t < 256) ws[chIdx(ell - 1, s, b) + t] = outrow[t];
    if (t == 0) {
        float M = scrm[0];
        #pragma unroll
        for (int i = 1; i < 8; i++) M = fmaxf(M, scrm[i]);
        ws[OFF_RMAX + (size_t)((ell - 1) * 16 + s) * 8 + b] = M;
    }
}

// ---------------- root ----------------
__global__ __launch_bounds__(256) void root_kernel(const float* __restrict__ root_w,
                                                   const float* __restrict__ root_b,
                                                   const float* __restrict__ ws,
                                                   float* __restrict__ out) {
    int b = blockIdx.x, t = threadIdx.x;
    __shared__ float scr[4];
    float rv = root_w[t] + root_b[t];
    float mroot = blockMax(rv, scr, 4);
    float sroot = blockSum(expf(rv - mroot), scr, 4);
    float lroot = mroot + logf(sroot);
    float v = ws[chIdx(T_ - 1, 0, b) + t] + rv - lroot;
    float m2 = blockMax(v, scr, 4);
    float s2 = blockSum(expf(v - m2), scr, 4);
    if (t == 0) out[b] = m2 + logf(s2);
}

extern "C" void kernel_launch(void* const* d_in, const int* in_sizes, int n_in,
                              void* d_out, int out_size, void* d_ws, size_t ws_size,
                              hipStream_t stream) {
    const int*   words   = (const int*)  d_in[0];
    const float* nt_emb  = (const float*)d_in[1];
    const float* W_emit  = (const float*)d_in[2];
    const float* b_emit  = (const float*)d_in[3];
    const float* rule_W  = (const float*)d_in[4];
    const float* rule_b  = (const float*)d_in[5];
    const float* assoc   = (const float*)d_in[6];
    const float* root_w  = (const float*)d_in[7];
    const float* root_b  = (const float*)d_in[8];
    const float* sw1     = (const float*)d_in[9];
    const float* sb1     = (const float*)d_in[10];
    const float* r1w1    = (const float*)d_in[11];
    const float* r1b1    = (const float*)d_in[12];
    const float* r1w2    = (const float*)d_in[13];
    const float* r1b2    = (const float*)d_in[14];
    const float* r2w1    = (const float*)d_in[15];
    const float* r2b1    = (const float*)d_in[16];
    const float* r2w2    = (const float*)d_in[17];
    const float* r2b2    = (const float*)d_in[18];
    const float* sw2     = (const float*)d_in[19];
    const float* sb2     = (const float*)d_in[20];
    const int*   lfunc   = (const int*)  d_in[21];
    const int*   rfunc   = (const int*)  d_in[22];
    const int*   argpc   = (const int*)  d_in[23];
    const int*   res2all = (const int*)  d_in[24];
    const float* larg_m  = (const float*)d_in[25];
    const float* rarg_m  = (const float*)d_in[26];
    float* ws  = (float*)d_ws;
    float* out = (float*)d_out;

    // zero the atomic accumulators + arrival counters (re-poisoned 0xAA each replay)
    hipMemsetAsync((char*)d_ws + OFF_ACC * 4, 0, (ACC_SZ + 960) * 4, stream);

    prep_g_kernel<<<dim3(QRES), dim3(QARG), 0, stream>>>(rule_W, rule_b, assoc, larg_m, rarg_m,
                                                         lfunc, rfunc, ws);
    mlp_kernel<<<dim3(QALL / 4), dim3(STATE), 0, stream>>>(nt_emb, sw1, sb1, r1w1, r1b1, r1w2, r1b2,
                                                           r2w1, r2b1, r2w2, r2b2, sw2, sb2, ws);
    emit_kernel<<<dim3(NWT, QALL / 64), dim3(256), 0, stream>>>(nt_emb, W_emit, b_emit, ws);
    lse_kernel<<<dim3(1), dim3(256), 0, stream>>>(ws);
    chart0_kernel<<<dim3(B_ * T_), dim3(256), 0, stream>>>(words, nt_emb, W_emit, b_emit, ws);
    int lvbase = 0;
    for (int ell = 2; ell <= T_; ell++) {
        int n = T_ - ell + 1;
        level_kernel<<<dim3(n * 8, 12), dim3(512), 0, stream>>>(ws, argpc, res2all, ell, lvbase);
        lvbase += n;
    }
    root_kernel<<<dim3(B_), dim3(256), 0, stream>>>(root_w, root_b, ws, out);
}